// Round 16
// baseline (254.862 us; speedup 1.0000x reference)
//
#include <hip/hip_runtime.h>
#include <hip/hip_bf16.h>

#define D_MODEL   1024
#define D_STATE   64
#define D_INNER   2048
#define NHEADS    32
#define CONV_DIM  2176
#define D_IN_PROJ 4256
#define NPAD      4352
#define BATCH     8
#define SEQ       1024
#define NROWS     8192
#define NCHUNK    8
#define CLEN      128

typedef __attribute__((ext_vector_type(8))) short bf16x8;
typedef __attribute__((ext_vector_type(4))) float f32x4;

__device__ __forceinline__ float bf2f(unsigned short u){
  unsigned v = ((unsigned)u) << 16;
  return __builtin_bit_cast(float, v);
}
__device__ __forceinline__ unsigned short f2bf(float f){
  __hip_bfloat16 h = __float2bfloat16(f);
  return __builtin_bit_cast(unsigned short, h);
}

// ---------------- convert x (fp32 -> bf16) ----------------
__global__ __launch_bounds__(256) void k_convert_x(const float* __restrict__ x,
                                                   unsigned short* __restrict__ xb){
  int i = blockIdx.x*256 + threadIdx.x;
  float4 v = ((const float4*)x)[i];
  ushort4 o;
  o.x = f2bf(v.x); o.y = f2bf(v.y); o.z = f2bf(v.z); o.w = f2bf(v.w);
  ((ushort4*)xb)[i] = o;
}

// ---------------- transpose W_in [K][N] -> bf16 [NPAD][K] -------------------
__global__ __launch_bounds__(256) void k_transpose_win(const float* __restrict__ W_in,
                                                       unsigned short* __restrict__ wt){
  __shared__ float tile[32][33];
  int n0 = blockIdx.x * 32;
  int k0 = blockIdx.y * 32;
  int tx = threadIdx.x & 31;
  int ty = threadIdx.x >> 5;
  #pragma unroll
  for (int i = 0; i < 4; ++i){
    int kk = ty + i*8;
    int n  = n0 + tx;
    tile[kk][tx] = (n < D_IN_PROJ) ? W_in[(size_t)(k0+kk)*D_IN_PROJ + n] : 0.f;
  }
  __syncthreads();
  #pragma unroll
  for (int i = 0; i < 4; ++i){
    int nn = ty + i*8;
    wt[(size_t)(n0+nn)*D_MODEL + k0 + tx] = f2bf(tile[tx][nn]);
  }
}

// ---------------- nwc[d] = norm_w[d] * sum_k W_out[d][k]*head_w[k] ----------
__global__ __launch_bounds__(256) void k_nwc(const float* __restrict__ W_out,
                                             const float* __restrict__ head_w,
                                             const float* __restrict__ norm_w,
                                             float* __restrict__ nwc){
  int d    = blockIdx.x*4 + (threadIdx.x >> 6);
  int lane = threadIdx.x & 63;
  const float* row = W_out + (size_t)d * D_MODEL;
  float s = 0.f;
  #pragma unroll
  for (int k = lane; k < D_MODEL; k += 64) s += row[k] * head_w[k];
  #pragma unroll
  for (int off = 32; off; off >>= 1) s += __shfl_down(s, off);
  if (lane == 0) nwc[d] = s * norm_w[d];
}

// ---------------- 256x256 bf16 GEMM: per-phase barriers (m201 style) --------
// 4 quadrant-phases/K-tile, 2 barriers/phase; counted vmcnt waits are placed
// INSIDE the preceding phase, before its ending barrier (cross-wave safety:
// vmcnt is per-wave, so a barrier must follow the wait before dependent reads).
__global__ __launch_bounds__(512, 1) void k_gemm256(const unsigned short* __restrict__ A,
                                                    const unsigned short* __restrict__ BT,
                                                    unsigned short* __restrict__ C){
  __shared__ unsigned short smem[65536];  // [2 buf][A 16384 | B 16384] elems
  int bid  = blockIdx.x;
  int lt   = (bid & 7) * 68 + (bid >> 3);      // XCD-chunked logical tile
  int m0   = (lt / 17) << 8;
  int n0   = (lt % 17) << 8;
  int tid  = threadIdx.x;
  int w    = tid >> 6, lane = tid & 63;
  int wr   = w >> 2, wc = w & 3;
  int stR  = tid >> 3;                         // staging row 0..63 per slab
  int stCs = (((tid & 7) ^ ((tid >> 3) & 7)) << 3);  // pre-swizzled src col
  int wb   = w << 9;                           // wave LDS piece (512 elems)
  int frow = lane & 15, fk = (lane >> 4) << 3;

  f32x4 acc[8][4];
  #pragma unroll
  for (int i = 0; i < 8; ++i)
    #pragma unroll
    for (int j = 0; j < 4; ++j) acc[i][j] = (f32x4){0.f,0.f,0.f,0.f};

  const unsigned short* sA0 = A  + (size_t)(m0 + stR)*D_MODEL + stCs;
  const unsigned short* sB0 = BT + (size_t)(n0 + stR)*D_MODEL + stCs;

#define GLD(dstOff, src) __builtin_amdgcn_global_load_lds( \
    (const __attribute__((address_space(1))) void*)(src), \
    (__attribute__((address_space(3))) void*)(smem + (dstOff) + wb), 16, 0, 0)
#define ISSA(bb,kt,i) GLD((bb)*32768 + (i)*4096, \
    sA0 + (size_t)(kt)*64 + (size_t)(i)*64*D_MODEL)
#define ISSB(bb,kt,i) GLD((bb)*32768 + 16384 + (i)*4096, \
    sB0 + (size_t)(kt)*64 + (size_t)(i)*64*D_MODEL)
#define RD8(base, r, col) (*(const bf16x8*)((base) + (r)*64 + ((col) ^ (((r)&7)<<3))))

  // prologue: tile 0 -> buf0; order B0,B1,B2,B3,A0,A2,A1,A3
  ISSB(0,0,0); ISSB(0,0,1); ISSB(0,0,2); ISSB(0,0,3);
  ISSA(0,0,0); ISSA(0,0,2); ISSA(0,0,1); ISSA(0,0,3);
  asm volatile("s_waitcnt vmcnt(2)" ::: "memory");   // B0-3,A0,A2 done
  __builtin_amdgcn_s_barrier();
  asm volatile("" ::: "memory");

  for (int t = 0; t < 16; ++t){
    int cur = t & 1, nxt = cur ^ 1;
    bool iss = (t < 15);
    const unsigned short* At = smem + cur*32768;
    const unsigned short* Bt = At + 16384;

// phase: ds_read frags -> issue stage loads -> barrier -> MFMA -> WAIT -> barrier
#define QPHASE(mh, nh, ISSUE_STMT, WAIT_STMT) { \
    bf16x8 aF[4][2], bQ[2][2]; \
    _Pragma("unroll") \
    for (int mi = 0; mi < 4; ++mi){ \
      int r = wr*128 + (mh)*64 + mi*16 + frow; \
      aF[mi][0] = RD8(At, r, fk); \
      aF[mi][1] = RD8(At, r, 32 + fk); \
    } \
    _Pragma("unroll") \
    for (int ni = 0; ni < 2; ++ni){ \
      int r = wc*64 + (nh)*32 + ni*16 + frow; \
      bQ[ni][0] = RD8(Bt, r, fk); \
      bQ[ni][1] = RD8(Bt, r, 32 + fk); \
    } \
    ISSUE_STMT; \
    asm volatile("" ::: "memory"); \
    __builtin_amdgcn_s_barrier(); \
    asm volatile("" ::: "memory"); \
    __builtin_amdgcn_s_setprio(1); \
    _Pragma("unroll") \
    for (int mi = 0; mi < 4; ++mi) \
      _Pragma("unroll") \
      for (int ni = 0; ni < 2; ++ni) \
        _Pragma("unroll") \
        for (int kki = 0; kki < 2; ++kki) \
          acc[(mh)*4+mi][(nh)*2+ni] = __builtin_amdgcn_mfma_f32_16x16x32_bf16( \
              aF[mi][kki], bQ[ni][kki], acc[(mh)*4+mi][(nh)*2+ni], 0, 0, 0); \
    __builtin_amdgcn_s_setprio(0); \
    WAIT_STMT; \
    asm volatile("" ::: "memory"); \
    __builtin_amdgcn_s_barrier(); \
    asm volatile("" ::: "memory"); }

    // Q0 (mh0,nh0): reads A0/A2,B of t; issue B0,B1 of t+1
    QPHASE(0, 0,
      if (iss){ ISSB(nxt, t+1, 0); ISSB(nxt, t+1, 1); }, )
    // Q1 (mh0,nh1): issue B2,B3 of t+1; WAIT drains A1,A3 of tile t
    QPHASE(0, 1,
      if (iss){ ISSB(nxt, t+1, 2); ISSB(nxt, t+1, 3); },
      if (iss) asm volatile("s_waitcnt vmcnt(4)" ::: "memory");
      else     asm volatile("s_waitcnt vmcnt(0)" ::: "memory"); )
    // Q2 (mh1,nh0): reads A1/A3 of t (safe: Q1's WAIT+barrier); issue A0,A2
    QPHASE(1, 0,
      if (iss){ ISSA(nxt, t+1, 0); ISSA(nxt, t+1, 2); }, )
    // Q3 (mh1,nh1): issue A1,A3; WAIT drains B0-3,A0,A2 of t+1
    QPHASE(1, 1,
      if (iss){ ISSA(nxt, t+1, 1); ISSA(nxt, t+1, 3); },
      if (iss) asm volatile("s_waitcnt vmcnt(2)" ::: "memory"); )
#undef QPHASE
  }
#undef GLD
#undef ISSA
#undef ISSB
#undef RD8

  int crow = (lane >> 4) << 2, ccol = lane & 15;
  #pragma unroll
  for (int mf = 0; mf < 8; ++mf)
    #pragma unroll
    for (int nf = 0; nf < 4; ++nf){
      size_t base = (size_t)(m0 + wr*128 + mf*16 + crow)*NPAD + (n0 + wc*64 + nf*16 + ccol);
      #pragma unroll
      for (int r = 0; r < 4; ++r)
        C[base + (size_t)r*NPAD] = f2bf(acc[mf][nf][r]);
    }
}

// ---------------- dt = softplus(raw + bias), transposed [bh][t] -------------
__global__ __launch_bounds__(256) void k_dtda(const unsigned short* __restrict__ zx,
                                              const float* __restrict__ dt_bias,
                                              float* __restrict__ dtb){
  int i = blockIdx.x*256 + threadIdx.x;
  int r = i >> 5, h = i & 31;
  float raw = bf2f(zx[(size_t)r*NPAD + D_INNER + CONV_DIM + h]) + dt_bias[h];
  float dt  = (raw > 20.f) ? raw : log1pf(expf(raw));
  int b = r >> 10, l = r & 1023;
  dtb[(b*32 + h)*1024 + l] = dt;
}

// ---------------- causal conv1d (4 taps) + SiLU, vectorized x8 --------------
__global__ __launch_bounds__(256) void k_conv(const unsigned short* __restrict__ zx,
                                              const float* __restrict__ conv_w,
                                              const float* __restrict__ conv_b,
                                              unsigned short* __restrict__ xbc,
                                              unsigned short* __restrict__ bc16){
  int r = blockIdx.x;
  int l = r & (SEQ - 1);
  for (int oc = threadIdx.x; oc < 272; oc += 256){
    int c = oc * 8;
    float acc[8];
    #pragma unroll
    for (int j = 0; j < 8; ++j) acc[j] = conv_b[c + j];
    #pragma unroll
    for (int k = 0; k < 4; ++k){
      int dl = l + k - 3;
      if (dl >= 0){
        bf16x8 v = *(const bf16x8*)(zx + (size_t)(r + k - 3)*NPAD + D_INNER + c);
        #pragma unroll
        for (int j = 0; j < 8; ++j)
          acc[j] = fmaf(bf2f((unsigned short)v[j]), conv_w[k*CONV_DIM + c + j], acc[j]);
      }
    }
    bf16x8 o;
    #pragma unroll
    for (int j = 0; j < 8; ++j){
      float s = acc[j] / (1.f + expf(-acc[j]));
      o[j] = (short)f2bf(s);
    }
    if (c < D_INNER) *(bf16x8*)(xbc  + (size_t)r*D_INNER + c) = o;
    else             *(bf16x8*)(bc16 + (size_t)r*128 + (c - D_INNER)) = o;
  }
}

// ---------------- per-chunk inclusive cumsum of dt + cumA -------------------
__global__ __launch_bounds__(64) void k_cs(const float* __restrict__ dtb,
                                           const float* __restrict__ A_log,
                                           float* __restrict__ csb,
                                           float* __restrict__ cumA){
  int id = blockIdx.x;                 // bh*8 + c
  int bh = id >> 3, c = id & 7;
  int h  = bh & 31;
  int l  = threadIdx.x;
  const float* src = dtb + (size_t)bh*1024 + (c << 7);
  float d0 = src[2*l], d1 = src[2*l + 1];
  float pr = d0 + d1;
  float s  = pr;
  #pragma unroll
  for (int off = 1; off < 64; off <<= 1){
    float n = __shfl_up(s, off);
    if (l >= off) s += n;
  }
  float excl = s - pr;
  csb[(size_t)id*128 + 2*l]     = excl + d0;
  csb[(size_t)id*128 + 2*l + 1] = excl + pr;
  if (l == 63){
    float A = -expf(A_log[h]);
    cumA[id] = expf(A * s);
  }
}

// ---------------- SSD pass 1: h_end_local[p][s] = (w*X)^T @ B ---------------
__global__ __launch_bounds__(256) void k_ssd1(const unsigned short* __restrict__ xbc,
                                              const unsigned short* __restrict__ bc16,
                                              const float* __restrict__ dtb,
                                              const float* __restrict__ csb,
                                              const float* __restrict__ A_log,
                                              unsigned short* __restrict__ hend){
  __shared__ __align__(16) unsigned short XTw[64*136];
  __shared__ __align__(16) unsigned short BTl[64*136];
  int id = blockIdx.x;
  int bh = id >> 3, c = id & 7;
  int b  = bh >> 5, h = bh & 31;
  int tid = threadIdx.x;
  int w = tid >> 6, l = tid & 63;
  float A = -expf(A_log[h]);
  int row0 = b*SEQ + (c << 7);
  float csT = csb[(size_t)id*128 + 127];

  #pragma unroll
  for (int it = 0; it < 4; ++it){
    int idx = it*256 + tid;
    int tau = idx >> 3, pb = idx & 7;
    bf16x8 v = *(const bf16x8*)(xbc + (size_t)(row0+tau)*D_INNER + h*64 + pb*8);
    float wgt = dtb[(size_t)bh*1024 + (c<<7) + tau]
              * expf(A*(csT - csb[(size_t)id*128 + tau]));
    #pragma unroll
    for (int j = 0; j < 8; ++j)
      XTw[(pb*8+j)*136 + tau] = f2bf(bf2f((unsigned short)v[j]) * wgt);
  }
  #pragma unroll
  for (int it = 0; it < 4; ++it){
    int idx = it*256 + tid;
    int tau = idx >> 3, sb = idx & 7;
    bf16x8 v = *(const bf16x8*)(bc16 + (size_t)(row0+tau)*128 + sb*8);
    #pragma unroll
    for (int j = 0; j < 8; ++j)
      BTl[(sb*8+j)*136 + tau] = (unsigned short)v[j];
  }
  __syncthreads();

  int fr = l & 15, fo = (l >> 4) << 3;
  f32x4 acc[4];
  #pragma unroll
  for (int n = 0; n < 4; ++n) acc[n] = (f32x4){0.f,0.f,0.f,0.f};
  #pragma unroll
  for (int kt = 0; kt < 4; ++kt){
    bf16x8 pf = *(const bf16x8*)(XTw + (w*16+fr)*136 + kt*32 + fo);
    #pragma unroll
    for (int n = 0; n < 4; ++n){
      bf16x8 qf = *(const bf16x8*)(BTl + (n*16+fr)*136 + kt*32 + fo);
      acc[n] = __builtin_amdgcn_mfma_f32_16x16x32_bf16(pf, qf, acc[n], 0, 0, 0);
    }
  }
  #pragma unroll
  for (int n = 0; n < 4; ++n)
    #pragma unroll
    for (int r = 0; r < 4; ++r){
      int p = w*16 + ((l>>4)<<2) + r;
      int s = n*16 + fr;
      hend[(size_t)id*4096 + p*64 + s] = f2bf(acc[n][r]);
    }
}

// ---------------- combine: carry chunk states (in-place hend -> h_init) -----
__global__ __launch_bounds__(256) void k_comb(unsigned short* __restrict__ hh,
                                              const float* __restrict__ cumA){
  int bh = blockIdx.x, tid = threadIdx.x;
  float carry[16];
  #pragma unroll
  for (int i = 0; i < 16; ++i) carry[i] = 0.f;
  #pragma unroll
  for (int c = 0; c < NCHUNK; ++c){
    size_t base = (((size_t)bh*NCHUNK + c) << 12) + tid*16;
    bf16x8 a0 = *(const bf16x8*)(hh + base);
    bf16x8 a1 = *(const bf16x8*)(hh + base + 8);
    float ca = cumA[bh*NCHUNK + c];
    float tmp[16];
    #pragma unroll
    for (int i = 0; i < 8; ++i){
      tmp[i]   = bf2f((unsigned short)a0[i]);
      tmp[8+i] = bf2f((unsigned short)a1[i]);
    }
    bf16x8 w0, w1;
    #pragma unroll
    for (int i = 0; i < 8; ++i){
      w0[i] = (short)f2bf(carry[i]);
      w1[i] = (short)f2bf(carry[8+i]);
    }
    *(bf16x8*)(hh + base)     = w0;
    *(bf16x8*)(hh + base + 8) = w1;
    #pragma unroll
    for (int i = 0; i < 16; ++i) carry[i] = tmp[i] + ca*carry[i];
  }
}

// ---------------- SSD pass 2: Y = (mask.(C B^T)) X + diag(a) (C h_init) -----
// z-gate fused into the output write: yb stores g = Y_total * silu(z).
__global__ __launch_bounds__(256, 2) void k_ssd2(const unsigned short* __restrict__ xbc,
                                                 const unsigned short* __restrict__ bc16,
                                                 const unsigned short* __restrict__ zx,
                                                 const float* __restrict__ dtb,
                                                 const float* __restrict__ csb,
                                                 const float* __restrict__ A_log,
                                                 const float* __restrict__ Dskip,
                                                 const unsigned short* __restrict__ hbuf,
                                                 unsigned short* __restrict__ yb){
  __shared__ __align__(16) unsigned short Cl[128*72];
  __shared__ __align__(16) unsigned short XTl[64*136];
  __shared__ __align__(16) unsigned short Gm[128*136];
  __shared__ float cs_l[128], dt_l[128], a_l[128];

  int id = blockIdx.x;
  int bh = id >> 3, c = id & 7;
  int b  = bh >> 5, h = bh & 31;
  int tid = threadIdx.x;
  int w = tid >> 6, l = tid & 63;
  float A = -expf(A_log[h]);
  int row0 = b*SEQ + (c << 7);

  #pragma unroll
  for (int it = 0; it < 4; ++it){
    int idx = it*256 + tid;
    int tau = idx >> 3, cb = idx & 7;
    bf16x8 v = *(const bf16x8*)(bc16 + (size_t)(row0+tau)*128 + 64 + cb*8);
    *(bf16x8*)(Cl + tau*72 + cb*8) = v;
  }
  #pragma unroll
  for (int it = 0; it < 4; ++it){
    int idx = it*256 + tid;
    int tau = idx >> 3, pb = idx & 7;
    bf16x8 v = *(const bf16x8*)(xbc + (size_t)(row0+tau)*D_INNER + h*64 + pb*8);
    #pragma unroll
    for (int j = 0; j < 8; ++j)
      XTl[(pb*8+j)*136 + tau] = (unsigned short)v[j];
  }
  if (tid < 128){
    float cs = csb[(size_t)id*128 + tid];
    cs_l[tid] = cs;
    dt_l[tid] = dtb[(size_t)bh*1024 + (c<<7) + tid];
    a_l[tid]  = expf(A*cs);
  }
  __syncthreads();

  int fr = l & 15, fo = (l >> 4) << 3;
  int mtB = 7 - w;

  f32x4 Y[2][4];
  #pragma unroll
  for (int mi = 0; mi < 2; ++mi)
    #pragma unroll
    for (int n = 0; n < 4; ++n) Y[mi][n] = (f32x4){0.f,0.f,0.f,0.f};
  #pragma unroll
  for (int mi = 0; mi < 2; ++mi){
    int mt = mi ? mtB : w;
    #pragma unroll
    for (int kt = 0; kt < 2; ++kt){
      bf16x8 pf = *(const bf16x8*)(Cl + (mt*16+fr)*72 + kt*32 + fo);
      #pragma unroll
      for (int n = 0; n < 4; ++n){
        bf16x8 qf = *(const bf16x8*)(hbuf + (size_t)id*4096 + (n*16+fr)*64 + kt*32 + fo);
        Y[mi][n] = __builtin_amdgcn_mfma_f32_16x16x32_bf16(pf, qf, Y[mi][n], 0, 0, 0);
      }
    }
    #pragma unroll
    for (int r = 0; r < 4; ++r){
      float av = a_l[mt*16 + ((l>>4)<<2) + r];
      #pragma unroll
      for (int n = 0; n < 4; ++n) Y[mi][n][r] *= av;
    }
  }

  f32x4 Sv[9];
  #pragma unroll
  for (int slot = 0; slot < 9; ++slot){
    int mt = (slot <= w) ? w : mtB;
    int nt = (slot <= w) ? slot : slot - w - 1;
    f32x4 acc = (f32x4){0.f,0.f,0.f,0.f};
    #pragma unroll
    for (int kt = 0; kt < 2; ++kt){
      bf16x8 pf = *(const bf16x8*)(Cl + (mt*16+fr)*72 + kt*32 + fo);
      bf16x8 qf = *(const bf16x8*)(bc16 + (size_t)(row0 + nt*16+fr)*128 + kt*32 + fo);
      acc = __builtin_amdgcn_mfma_f32_16x16x32_bf16(pf, qf, acc, 0, 0, 0);
    }
    int tau = nt*16 + fr;
    float dtt = dt_l[tau];
    float cst = cs_l[tau];
    #pragma unroll
    for (int r = 0; r < 4; ++r){
      int t = mt*16 + ((l>>4)<<2) + r;
      float v = acc[r] * dtt * expf(A*(cs_l[t] - cst));
      acc[r] = (tau <= t) ? v : 0.f;
    }
    Sv[slot] = acc;
  }

  #pragma unroll
  for (int slot = 0; slot < 9; ++slot){
    int mt = (slot <= w) ? w : mtB;
    int nt = (slot <= w) ? slot : slot - w - 1;
    int tau = nt*16 + fr;
    #pragma unroll
    for (int r = 0; r < 4; ++r){
      int t = mt*16 + ((l>>4)<<2) + r;
      Gm[t*136 + tau] = f2bf(Sv[slot][r]);
    }
  }
  {
    int mtE = (w & 1) ? mtB : w;
    int ntE = mtE + 1;
    #pragma unroll
    for (int r = 0; r < 4; ++r){
      int t = mtE*16 + ((l>>4)<<2) + r;
      Gm[t*136 + ntE*16 + fr] = 0;
    }
  }
  __syncthreads();

  #pragma unroll
  for (int mi = 0; mi < 2; ++mi){
    int mt = mi ? mtB : w;
    int kmax = (mt + 2) >> 1;
    for (int kt2 = 0; kt2 < kmax; ++kt2){
      bf16x8 pf = *(const bf16x8*)(Gm + (mt*16+fr)*136 + kt2*32 + fo);
      #pragma unroll
      for (int n = 0; n < 4; ++n){
        bf16x8 qf = *(const bf16x8*)(XTl + (n*16+fr)*136 + kt2*32 + fo);
        Y[mi][n] = __builtin_amdgcn_mfma_f32_16x16x32_bf16(pf, qf, Y[mi][n], 0, 0, 0);
      }
    }
  }

  // output: g = (Y + Dskip*x) * silu(z)   [z-gate fused]
  float dsk = Dskip[h];
  #pragma unroll
  for (int mi = 0; mi < 2; ++mi){
    int mt = mi ? mtB : w;
    #pragma unroll
    for (int r = 0; r < 4; ++r){
      int t = mt*16 + ((l>>4)<<2) + r;
      size_t orow = (size_t)(row0 + t)*D_INNER + h*64;
      size_t zrow = (size_t)(row0 + t)*NPAD + h*64;
      #pragma unroll
      for (int n = 0; n < 4; ++n){
        int p = n*16 + fr;
        float xv = bf2f(XTl[p*136 + t]);
        float zf = bf2f(zx[zrow + p]);
        float yv = Y[mi][n][r] + dsk*xv;
        float g  = yv * (zf / (1.f + expf(-zf)));
        yb[orow + p] = f2bf(g);
      }
    }
  }
}

// ---------------- fused RMS + (norm_w*W_out@head_w) dot on gated y ----------
__global__ __launch_bounds__(256) void k_epilogue(const unsigned short* __restrict__ yg,
                                                  const float* __restrict__ nwc,
                                                  const float* __restrict__ head_b,
                                                  float* __restrict__ out){
  int r   = blockIdx.x;
  int tid = threadIdx.x;
  bf16x8 y8 = *(const bf16x8*)(yg + (size_t)r*D_INNER + tid*8);
  float4 w0 = ((const float4*)nwc)[tid*2];
  float4 w1 = ((const float4*)nwc)[tid*2 + 1];
  float wv[8] = {w0.x, w0.y, w0.z, w0.w, w1.x, w1.y, w1.z, w1.w};
  float s2 = 0.f, sd = 0.f;
  #pragma unroll
  for (int k = 0; k < 8; ++k){
    float g = bf2f((unsigned short)y8[k]);
    s2 += g*g; sd += g*wv[k];
  }
  #pragma unroll
  for (int off = 32; off; off >>= 1){
    s2 += __shfl_down(s2, off);
    sd += __shfl_down(sd, off);
  }
  __shared__ float r2[4], rd[4];
  if ((tid & 63) == 0){ r2[tid >> 6] = s2; rd[tid >> 6] = sd; }
  __syncthreads();
  if (tid == 0){
    float t2 = r2[0] + r2[1] + r2[2] + r2[3];
    float td = rd[0] + rd[1] + rd[2] + rd[3];
    out[r] = rsqrtf(t2 * (1.f/2048.f) + 1e-5f) * td + head_b[0];
  }
}

extern "C" void kernel_launch(void* const* d_in, const int* in_sizes, int n_in,
                              void* d_out, int out_size, void* d_ws, size_t ws_size,
                              hipStream_t stream){
  const float* x       = (const float*)d_in[0];
  const float* W_in    = (const float*)d_in[1];
  const float* conv_w  = (const float*)d_in[2];
  const float* conv_b  = (const float*)d_in[3];
  const float* dt_bias = (const float*)d_in[4];
  const float* A_log   = (const float*)d_in[5];
  const float* Dskip   = (const float*)d_in[6];
  const float* norm_w  = (const float*)d_in[7];
  const float* W_out   = (const float*)d_in[8];
  const float* head_w  = (const float*)d_in[9];
  const float* head_b  = (const float*)d_in[10];
  float* out = (float*)d_out;

  char* ws = (char*)d_ws;
  unsigned short* xb   = (unsigned short*)(ws + 0);            // 16,777,216 (reused: hbuf)
  unsigned short* wt   = (unsigned short*)(ws + 16777216);     //  8,912,896 W_in^T (reused: bc16|csb|cumA)
  unsigned short* zx16 = (unsigned short*)(ws + 25690112);     // 71,303,168
  unsigned short* xbc  = (unsigned short*)(ws + 96993280);     // 33,554,432 ([r][2048] x only)
  float*          dtb  = (float*)         (ws + 132644864);    //  1,048,576
  float*          nwc  = (float*)         (ws + 134742016);    //      8,192
  unsigned short* yb   = (unsigned short*)(ws + 134750208);    // 33,554,432

  unsigned short* hbuf = xb;                                   // 2048*4096*2B
  unsigned short* bc16 = wt;                                   // 8192*128*2B = 2,097,152
  float*          csb  = (float*)(ws + 16777216 + 2097152);    // 2048*128*4B
  float*          cumA = (float*)(ws + 16777216 + 3145728);    // 8,192

  k_convert_x<<<8192, 256, 0, stream>>>(x, xb);
  k_transpose_win<<<dim3(136, 32), 256, 0, stream>>>(W_in, wt);
  k_nwc<<<512, 256, 0, stream>>>(W_out, head_w, norm_w, nwc);
  k_gemm256<<<(NROWS/256)*(NPAD/256), 512, 0, stream>>>(xb, wt, zx16);
  k_dtda<<<1024, 256, 0, stream>>>(zx16, dt_bias, dtb);
  k_conv<<<NROWS, 256, 0, stream>>>(zx16, conv_w, conv_b, xbc, bc16);
  k_cs<<<2048, 64, 0, stream>>>(dtb, A_log, csb, cumA);
  k_ssd1<<<2048, 256, 0, stream>>>(xbc, bc16, dtb, csb, A_log, hbuf);
  k_comb<<<256, 256, 0, stream>>>(hbuf, cumA);
  k_ssd2<<<2048, 256, 0, stream>>>(xbc, bc16, zx16, dtb, csb, A_log, Dskip, hbuf, yb);
  k_epilogue<<<NROWS, 256, 0, stream>>>(yb, nwc, head_b, out);
}

// Round 17
// 241.992 us; speedup vs baseline: 1.0532x; 1.0532x over previous
//
#include <hip/hip_runtime.h>
#include <hip/hip_bf16.h>

#define D_MODEL   1024
#define D_STATE   64
#define D_INNER   2048
#define NHEADS    32
#define CONV_DIM  2176
#define D_IN_PROJ 4256
#define NPAD      4352
#define BATCH     8
#define SEQ       1024
#define NROWS     8192
#define NCHUNK    8
#define CLEN      128

typedef __attribute__((ext_vector_type(8))) short bf16x8;
typedef __attribute__((ext_vector_type(4))) float f32x4;

__device__ __forceinline__ float bf2f(unsigned short u){
  unsigned v = ((unsigned)u) << 16;
  return __builtin_bit_cast(float, v);
}
__device__ __forceinline__ unsigned short f2bf(float f){
  __hip_bfloat16 h = __float2bfloat16(f);
  return __builtin_bit_cast(unsigned short, h);
}

// ---------------- fused prep: convert x | transpose W_in | nwc --------------
// grid 13056 x 256: [0,8192) convert_x, [8192,12544) transpose, [12544,13056) nwc
__global__ __launch_bounds__(256) void k_prep(const float* __restrict__ x,
                                              const float* __restrict__ W_in,
                                              const float* __restrict__ W_out,
                                              const float* __restrict__ head_w,
                                              const float* __restrict__ norm_w,
                                              unsigned short* __restrict__ xb,
                                              unsigned short* __restrict__ wt,
                                              float* __restrict__ nwc){
  int blk = blockIdx.x;
  if (blk < 8192){
    int i = blk*256 + threadIdx.x;
    float4 v = ((const float4*)x)[i];
    ushort4 o;
    o.x = f2bf(v.x); o.y = f2bf(v.y); o.z = f2bf(v.z); o.w = f2bf(v.w);
    ((ushort4*)xb)[i] = o;
  } else if (blk < 12544){
    __shared__ float tile[32][33];
    int bx = blk - 8192;
    int n0 = (bx % 136) * 32;
    int k0 = (bx / 136) * 32;
    int tx = threadIdx.x & 31;
    int ty = threadIdx.x >> 5;
    #pragma unroll
    for (int i = 0; i < 4; ++i){
      int kk = ty + i*8;
      int n  = n0 + tx;
      tile[kk][tx] = (n < D_IN_PROJ) ? W_in[(size_t)(k0+kk)*D_IN_PROJ + n] : 0.f;
    }
    __syncthreads();
    #pragma unroll
    for (int i = 0; i < 4; ++i){
      int nn = ty + i*8;
      wt[(size_t)(n0+nn)*D_MODEL + k0 + tx] = f2bf(tile[tx][nn]);
    }
  } else {
    int d    = (blk - 12544)*4 + (threadIdx.x >> 6);
    int lane = threadIdx.x & 63;
    const float* row = W_out + (size_t)d * D_MODEL;
    float s = 0.f;
    #pragma unroll
    for (int k = lane; k < D_MODEL; k += 64) s += row[k] * head_w[k];
    #pragma unroll
    for (int off = 32; off; off >>= 1) s += __shfl_down(s, off);
    if (lane == 0) nwc[d] = s * norm_w[d];
  }
}

// ---------------- 256x256 bf16 GEMM (round-14 config: best measured) --------
// 4 phases/K-tile, 2 barriers/tile, counted vmcnt(4)/(2); LDS read/source
// swizzle; XCD-chunked block swizzle. 8 waves (2Mx4N), per-wave 128x64 out.
__global__ __launch_bounds__(512, 1) void k_gemm256(const unsigned short* __restrict__ A,
                                                    const unsigned short* __restrict__ BT,
                                                    unsigned short* __restrict__ C){
  __shared__ unsigned short smem[65536];  // [2 buf][A 16384 | B 16384] elems
  int bid  = blockIdx.x;
  int lt   = (bid & 7) * 68 + (bid >> 3);      // XCD-chunked logical tile
  int m0   = (lt / 17) << 8;
  int n0   = (lt % 17) << 8;
  int tid  = threadIdx.x;
  int w    = tid >> 6, lane = tid & 63;
  int wr   = w >> 2, wc = w & 3;
  int stR  = tid >> 3;                         // staging row 0..63 per slab
  int stCs = (((tid & 7) ^ ((tid >> 3) & 7)) << 3);  // pre-swizzled src col
  int wb   = w << 9;                           // wave LDS piece (512 elems)
  int frow = lane & 15, fk = (lane >> 4) << 3;

  f32x4 acc[8][4];
  #pragma unroll
  for (int i = 0; i < 8; ++i)
    #pragma unroll
    for (int j = 0; j < 4; ++j) acc[i][j] = (f32x4){0.f,0.f,0.f,0.f};

  const unsigned short* sA0 = A  + (size_t)(m0 + stR)*D_MODEL + stCs;
  const unsigned short* sB0 = BT + (size_t)(n0 + stR)*D_MODEL + stCs;

#define GLD(dstOff, src) __builtin_amdgcn_global_load_lds( \
    (const __attribute__((address_space(1))) void*)(src), \
    (__attribute__((address_space(3))) void*)(smem + (dstOff) + wb), 16, 0, 0)
#define ISSA(bb,kt,i) GLD((bb)*32768 + (i)*4096, \
    sA0 + (size_t)(kt)*64 + (size_t)(i)*64*D_MODEL)
#define ISSB(bb,kt,i) GLD((bb)*32768 + 16384 + (i)*4096, \
    sB0 + (size_t)(kt)*64 + (size_t)(i)*64*D_MODEL)
#define RD8(base, r, col) (*(const bf16x8*)((base) + (r)*64 + ((col) ^ (((r)&7)<<3))))

  // prologue: tile 0 -> buf0; order B0,B1,B2,B3,A0,A2,A1,A3
  ISSB(0,0,0); ISSB(0,0,1); ISSB(0,0,2); ISSB(0,0,3);
  ISSA(0,0,0); ISSA(0,0,2); ISSA(0,0,1); ISSA(0,0,3);
  asm volatile("s_waitcnt vmcnt(2)" ::: "memory");   // B0-3,A0,A2 done
  __builtin_amdgcn_s_barrier();
  asm volatile("" ::: "memory");

  for (int t = 0; t < 16; ++t){
    int cur = t & 1, nxt = cur ^ 1;
    bool iss = (t < 15);
    const unsigned short* At = smem + cur*32768;
    const unsigned short* Bt = At + 16384;

    bf16x8 bF[4][2];
    // ---------------- P0: mf 0-1 -------------------------------------------
    if (iss){ ISSB(nxt, t+1, 0); ISSB(nxt, t+1, 1); }
    #pragma unroll
    for (int nf = 0; nf < 4; ++nf){
      int r = wc*64 + nf*16 + frow;
      bF[nf][0] = RD8(Bt, r, fk);
      bF[nf][1] = RD8(Bt, r, 32 + fk);
    }
    {
      bf16x8 aF[2][2];
      #pragma unroll
      for (int mi = 0; mi < 2; ++mi){
        int r = wr*128 + mi*16 + frow;
        aF[mi][0] = RD8(At, r, fk);
        aF[mi][1] = RD8(At, r, 32 + fk);
      }
      __builtin_amdgcn_s_setprio(1);
      #pragma unroll
      for (int mi = 0; mi < 2; ++mi)
        #pragma unroll
        for (int nf = 0; nf < 4; ++nf)
          #pragma unroll
          for (int kki = 0; kki < 2; ++kki)
            acc[mi][nf] = __builtin_amdgcn_mfma_f32_16x16x32_bf16(aF[mi][kki], bF[nf][kki], acc[mi][nf], 0, 0, 0);
      __builtin_amdgcn_s_setprio(0);
    }
    // ---------------- P1: mf 2-3 -------------------------------------------
    if (iss){ ISSB(nxt, t+1, 2); ISSB(nxt, t+1, 3); }
    {
      bf16x8 aF[2][2];
      #pragma unroll
      for (int mi = 0; mi < 2; ++mi){
        int r = wr*128 + (2 + mi)*16 + frow;
        aF[mi][0] = RD8(At, r, fk);
        aF[mi][1] = RD8(At, r, 32 + fk);
      }
      __builtin_amdgcn_s_setprio(1);
      #pragma unroll
      for (int mi = 0; mi < 2; ++mi)
        #pragma unroll
        for (int nf = 0; nf < 4; ++nf)
          #pragma unroll
          for (int kki = 0; kki < 2; ++kki)
            acc[2 + mi][nf] = __builtin_amdgcn_mfma_f32_16x16x32_bf16(aF[mi][kki], bF[nf][kki], acc[2 + mi][nf], 0, 0, 0);
      __builtin_amdgcn_s_setprio(0);
    }
    if (iss) asm volatile("s_waitcnt vmcnt(4)" ::: "memory");
    else     asm volatile("s_waitcnt vmcnt(0)" ::: "memory");
    __builtin_amdgcn_s_barrier();
    asm volatile("" ::: "memory");
    // ---------------- P2: mf 4-5 -------------------------------------------
    if (iss){ ISSA(nxt, t+1, 0); ISSA(nxt, t+1, 2); }
    {
      bf16x8 aF[2][2];
      #pragma unroll
      for (int mi = 0; mi < 2; ++mi){
        int r = wr*128 + (4 + mi)*16 + frow;
        aF[mi][0] = RD8(At, r, fk);
        aF[mi][1] = RD8(At, r, 32 + fk);
      }
      __builtin_amdgcn_s_setprio(1);
      #pragma unroll
      for (int mi = 0; mi < 2; ++mi)
        #pragma unroll
        for (int nf = 0; nf < 4; ++nf)
          #pragma unroll
          for (int kki = 0; kki < 2; ++kki)
            acc[4 + mi][nf] = __builtin_amdgcn_mfma_f32_16x16x32_bf16(aF[mi][kki], bF[nf][kki], acc[4 + mi][nf], 0, 0, 0);
      __builtin_amdgcn_s_setprio(0);
    }
    // ---------------- P3: mf 6-7 -------------------------------------------
    if (iss){ ISSA(nxt, t+1, 1); ISSA(nxt, t+1, 3); }
    {
      bf16x8 aF[2][2];
      #pragma unroll
      for (int mi = 0; mi < 2; ++mi){
        int r = wr*128 + (6 + mi)*16 + frow;
        aF[mi][0] = RD8(At, r, fk);
        aF[mi][1] = RD8(At, r, 32 + fk);
      }
      __builtin_amdgcn_s_setprio(1);
      #pragma unroll
      for (int mi = 0; mi < 2; ++mi)
        #pragma unroll
        for (int nf = 0; nf < 4; ++nf)
          #pragma unroll
          for (int kki = 0; kki < 2; ++kki)
            acc[6 + mi][nf] = __builtin_amdgcn_mfma_f32_16x16x32_bf16(aF[mi][kki], bF[nf][kki], acc[6 + mi][nf], 0, 0, 0);
      __builtin_amdgcn_s_setprio(0);
    }
    if (iss) asm volatile("s_waitcnt vmcnt(2)" ::: "memory");
    else     asm volatile("s_waitcnt vmcnt(0)" ::: "memory");
    __builtin_amdgcn_s_barrier();
    asm volatile("" ::: "memory");
  }
#undef GLD
#undef ISSA
#undef ISSB
#undef RD8

  int crow = (lane >> 4) << 2, ccol = lane & 15;
  #pragma unroll
  for (int mf = 0; mf < 8; ++mf)
    #pragma unroll
    for (int nf = 0; nf < 4; ++nf){
      size_t base = (size_t)(m0 + wr*128 + mf*16 + crow)*NPAD + (n0 + wc*64 + nf*16 + ccol);
      #pragma unroll
      for (int r = 0; r < 4; ++r)
        C[base + (size_t)r*NPAD] = f2bf(acc[mf][nf][r]);
    }
}

// ---------------- fused dt-softplus + per-chunk cumsum + cumA ---------------
// grid 2048 (bh*8+c), block 64; lane l owns timesteps 2l, 2l+1 of the chunk.
__global__ __launch_bounds__(64) void k_dtcs(const unsigned short* __restrict__ zx,
                                             const float* __restrict__ dt_bias,
                                             const float* __restrict__ A_log,
                                             float* __restrict__ dtb,
                                             float* __restrict__ csb,
                                             float* __restrict__ cumA){
  int id = blockIdx.x;
  int bh = id >> 3, c = id & 7;
  int b  = bh >> 5, h = bh & 31;
  int l  = threadIdx.x;
  int t0 = c << 7;
  size_t r0 = (size_t)(b*SEQ + t0 + 2*l);
  float bias = dt_bias[h];
  float raw0 = bf2f(zx[r0*NPAD + D_INNER + CONV_DIM + h]) + bias;
  float raw1 = bf2f(zx[(r0+1)*NPAD + D_INNER + CONV_DIM + h]) + bias;
  float d0 = (raw0 > 20.f) ? raw0 : log1pf(expf(raw0));
  float d1 = (raw1 > 20.f) ? raw1 : log1pf(expf(raw1));
  dtb[(size_t)bh*1024 + t0 + 2*l]     = d0;
  dtb[(size_t)bh*1024 + t0 + 2*l + 1] = d1;
  float pr = d0 + d1;
  float s  = pr;
  #pragma unroll
  for (int off = 1; off < 64; off <<= 1){
    float n = __shfl_up(s, off);
    if (l >= off) s += n;
  }
  float excl = s - pr;
  csb[(size_t)id*128 + 2*l]     = excl + d0;
  csb[(size_t)id*128 + 2*l + 1] = excl + pr;
  if (l == 63){
    float A = -expf(A_log[h]);
    cumA[id] = expf(A * s);
  }
}

// ---------------- causal conv1d (4 taps) + SiLU, vectorized x8 --------------
__global__ __launch_bounds__(256) void k_conv(const unsigned short* __restrict__ zx,
                                              const float* __restrict__ conv_w,
                                              const float* __restrict__ conv_b,
                                              unsigned short* __restrict__ xbc,
                                              unsigned short* __restrict__ bc16){
  int r = blockIdx.x;
  int l = r & (SEQ - 1);
  for (int oc = threadIdx.x; oc < 272; oc += 256){
    int c = oc * 8;
    float acc[8];
    #pragma unroll
    for (int j = 0; j < 8; ++j) acc[j] = conv_b[c + j];
    #pragma unroll
    for (int k = 0; k < 4; ++k){
      int dl = l + k - 3;
      if (dl >= 0){
        bf16x8 v = *(const bf16x8*)(zx + (size_t)(r + k - 3)*NPAD + D_INNER + c);
        #pragma unroll
        for (int j = 0; j < 8; ++j)
          acc[j] = fmaf(bf2f((unsigned short)v[j]), conv_w[k*CONV_DIM + c + j], acc[j]);
      }
    }
    bf16x8 o;
    #pragma unroll
    for (int j = 0; j < 8; ++j){
      float s = acc[j] / (1.f + expf(-acc[j]));
      o[j] = (short)f2bf(s);
    }
    if (c < D_INNER) *(bf16x8*)(xbc  + (size_t)r*D_INNER + c) = o;
    else             *(bf16x8*)(bc16 + (size_t)r*128 + (c - D_INNER)) = o;
  }
}

// ---------------- SSD pass 1: h_end_local[p][s] = (w*X)^T @ B ---------------
__global__ __launch_bounds__(256) void k_ssd1(const unsigned short* __restrict__ xbc,
                                              const unsigned short* __restrict__ bc16,
                                              const float* __restrict__ dtb,
                                              const float* __restrict__ csb,
                                              const float* __restrict__ A_log,
                                              unsigned short* __restrict__ hend){
  __shared__ __align__(16) unsigned short XTw[64*136];
  __shared__ __align__(16) unsigned short BTl[64*136];
  int id = blockIdx.x;
  int bh = id >> 3, c = id & 7;
  int b  = bh >> 5, h = bh & 31;
  int tid = threadIdx.x;
  int w = tid >> 6, l = tid & 63;
  float A = -expf(A_log[h]);
  int row0 = b*SEQ + (c << 7);
  float csT = csb[(size_t)id*128 + 127];

  #pragma unroll
  for (int it = 0; it < 4; ++it){
    int idx = it*256 + tid;
    int tau = idx >> 3, pb = idx & 7;
    bf16x8 v = *(const bf16x8*)(xbc + (size_t)(row0+tau)*D_INNER + h*64 + pb*8);
    float wgt = dtb[(size_t)bh*1024 + (c<<7) + tau]
              * expf(A*(csT - csb[(size_t)id*128 + tau]));
    #pragma unroll
    for (int j = 0; j < 8; ++j)
      XTw[(pb*8+j)*136 + tau] = f2bf(bf2f((unsigned short)v[j]) * wgt);
  }
  #pragma unroll
  for (int it = 0; it < 4; ++it){
    int idx = it*256 + tid;
    int tau = idx >> 3, sb = idx & 7;
    bf16x8 v = *(const bf16x8*)(bc16 + (size_t)(row0+tau)*128 + sb*8);
    #pragma unroll
    for (int j = 0; j < 8; ++j)
      BTl[(sb*8+j)*136 + tau] = (unsigned short)v[j];
  }
  __syncthreads();

  int fr = l & 15, fo = (l >> 4) << 3;
  f32x4 acc[4];
  #pragma unroll
  for (int n = 0; n < 4; ++n) acc[n] = (f32x4){0.f,0.f,0.f,0.f};
  #pragma unroll
  for (int kt = 0; kt < 4; ++kt){
    bf16x8 pf = *(const bf16x8*)(XTw + (w*16+fr)*136 + kt*32 + fo);
    #pragma unroll
    for (int n = 0; n < 4; ++n){
      bf16x8 qf = *(const bf16x8*)(BTl + (n*16+fr)*136 + kt*32 + fo);
      acc[n] = __builtin_amdgcn_mfma_f32_16x16x32_bf16(pf, qf, acc[n], 0, 0, 0);
    }
  }
  #pragma unroll
  for (int n = 0; n < 4; ++n)
    #pragma unroll
    for (int r = 0; r < 4; ++r){
      int p = w*16 + ((l>>4)<<2) + r;
      int s = n*16 + fr;
      hend[(size_t)id*4096 + p*64 + s] = f2bf(acc[n][r]);
    }
}

// ---------------- combine: carry chunk states (in-place hend -> h_init) -----
__global__ __launch_bounds__(256) void k_comb(unsigned short* __restrict__ hh,
                                              const float* __restrict__ cumA){
  int bh = blockIdx.x, tid = threadIdx.x;
  float carry[16];
  #pragma unroll
  for (int i = 0; i < 16; ++i) carry[i] = 0.f;
  #pragma unroll
  for (int c = 0; c < NCHUNK; ++c){
    size_t base = (((size_t)bh*NCHUNK + c) << 12) + tid*16;
    bf16x8 a0 = *(const bf16x8*)(hh + base);
    bf16x8 a1 = *(const bf16x8*)(hh + base + 8);
    float ca = cumA[bh*NCHUNK + c];
    float tmp[16];
    #pragma unroll
    for (int i = 0; i < 8; ++i){
      tmp[i]   = bf2f((unsigned short)a0[i]);
      tmp[8+i] = bf2f((unsigned short)a1[i]);
    }
    bf16x8 w0, w1;
    #pragma unroll
    for (int i = 0; i < 8; ++i){
      w0[i] = (short)f2bf(carry[i]);
      w1[i] = (short)f2bf(carry[8+i]);
    }
    *(bf16x8*)(hh + base)     = w0;
    *(bf16x8*)(hh + base + 8) = w1;
    #pragma unroll
    for (int i = 0; i < 16; ++i) carry[i] = tmp[i] + ca*carry[i];
  }
}

// ---------------- SSD pass 2: Y = (mask.(C B^T)) X + diag(a) (C h_init) -----
// z-gate fused into the output write: yb stores g = Y_total * silu(z).
__global__ __launch_bounds__(256, 2) void k_ssd2(const unsigned short* __restrict__ xbc,
                                                 const unsigned short* __restrict__ bc16,
                                                 const unsigned short* __restrict__ zx,
                                                 const float* __restrict__ dtb,
                                                 const float* __restrict__ csb,
                                                 const float* __restrict__ A_log,
                                                 const float* __restrict__ Dskip,
                                                 const unsigned short* __restrict__ hbuf,
                                                 unsigned short* __restrict__ yb){
  __shared__ __align__(16) unsigned short Cl[128*72];
  __shared__ __align__(16) unsigned short XTl[64*136];
  __shared__ __align__(16) unsigned short Gm[128*136];
  __shared__ float cs_l[128], dt_l[128], a_l[128];

  int id = blockIdx.x;
  int bh = id >> 3, c = id & 7;
  int b  = bh >> 5, h = bh & 31;
  int tid = threadIdx.x;
  int w = tid >> 6, l = tid & 63;
  float A = -expf(A_log[h]);
  int row0 = b*SEQ + (c << 7);

  #pragma unroll
  for (int it = 0; it < 4; ++it){
    int idx = it*256 + tid;
    int tau = idx >> 3, cb = idx & 7;
    bf16x8 v = *(const bf16x8*)(bc16 + (size_t)(row0+tau)*128 + 64 + cb*8);
    *(bf16x8*)(Cl + tau*72 + cb*8) = v;
  }
  #pragma unroll
  for (int it = 0; it < 4; ++it){
    int idx = it*256 + tid;
    int tau = idx >> 3, pb = idx & 7;
    bf16x8 v = *(const bf16x8*)(xbc + (size_t)(row0+tau)*D_INNER + h*64 + pb*8);
    #pragma unroll
    for (int j = 0; j < 8; ++j)
      XTl[(pb*8+j)*136 + tau] = (unsigned short)v[j];
  }
  if (tid < 128){
    float cs = csb[(size_t)id*128 + tid];
    cs_l[tid] = cs;
    dt_l[tid] = dtb[(size_t)bh*1024 + (c<<7) + tid];
    a_l[tid]  = expf(A*cs);
  }
  __syncthreads();

  int fr = l & 15, fo = (l >> 4) << 3;
  int mtB = 7 - w;

  f32x4 Y[2][4];
  #pragma unroll
  for (int mi = 0; mi < 2; ++mi)
    #pragma unroll
    for (int n = 0; n < 4; ++n) Y[mi][n] = (f32x4){0.f,0.f,0.f,0.f};
  #pragma unroll
  for (int mi = 0; mi < 2; ++mi){
    int mt = mi ? mtB : w;
    #pragma unroll
    for (int kt = 0; kt < 2; ++kt){
      bf16x8 pf = *(const bf16x8*)(Cl + (mt*16+fr)*72 + kt*32 + fo);
      #pragma unroll
      for (int n = 0; n < 4; ++n){
        bf16x8 qf = *(const bf16x8*)(hbuf + (size_t)id*4096 + (n*16+fr)*64 + kt*32 + fo);
        Y[mi][n] = __builtin_amdgcn_mfma_f32_16x16x32_bf16(pf, qf, Y[mi][n], 0, 0, 0);
      }
    }
    #pragma unroll
    for (int r = 0; r < 4; ++r){
      float av = a_l[mt*16 + ((l>>4)<<2) + r];
      #pragma unroll
      for (int n = 0; n < 4; ++n) Y[mi][n][r] *= av;
    }
  }

  f32x4 Sv[9];
  #pragma unroll
  for (int slot = 0; slot < 9; ++slot){
    int mt = (slot <= w) ? w : mtB;
    int nt = (slot <= w) ? slot : slot - w - 1;
    f32x4 acc = (f32x4){0.f,0.f,0.f,0.f};
    #pragma unroll
    for (int kt = 0; kt < 2; ++kt){
      bf16x8 pf = *(const bf16x8*)(Cl + (mt*16+fr)*72 + kt*32 + fo);
      bf16x8 qf = *(const bf16x8*)(bc16 + (size_t)(row0 + nt*16+fr)*128 + kt*32 + fo);
      acc = __builtin_amdgcn_mfma_f32_16x16x32_bf16(pf, qf, acc, 0, 0, 0);
    }
    int tau = nt*16 + fr;
    float dtt = dt_l[tau];
    float cst = cs_l[tau];
    #pragma unroll
    for (int r = 0; r < 4; ++r){
      int t = mt*16 + ((l>>4)<<2) + r;
      float v = acc[r] * dtt * expf(A*(cs_l[t] - cst));
      acc[r] = (tau <= t) ? v : 0.f;
    }
    Sv[slot] = acc;
  }

  #pragma unroll
  for (int slot = 0; slot < 9; ++slot){
    int mt = (slot <= w) ? w : mtB;
    int nt = (slot <= w) ? slot : slot - w - 1;
    int tau = nt*16 + fr;
    #pragma unroll
    for (int r = 0; r < 4; ++r){
      int t = mt*16 + ((l>>4)<<2) + r;
      Gm[t*136 + tau] = f2bf(Sv[slot][r]);
    }
  }
  {
    int mtE = (w & 1) ? mtB : w;
    int ntE = mtE + 1;
    #pragma unroll
    for (int r = 0; r < 4; ++r){
      int t = mtE*16 + ((l>>4)<<2) + r;
      Gm[t*136 + ntE*16 + fr] = 0;
    }
  }
  __syncthreads();

  #pragma unroll
  for (int mi = 0; mi < 2; ++mi){
    int mt = mi ? mtB : w;
    int kmax = (mt + 2) >> 1;
    for (int kt2 = 0; kt2 < kmax; ++kt2){
      bf16x8 pf = *(const bf16x8*)(Gm + (mt*16+fr)*136 + kt2*32 + fo);
      #pragma unroll
      for (int n = 0; n < 4; ++n){
        bf16x8 qf = *(const bf16x8*)(XTl + (n*16+fr)*136 + kt2*32 + fo);
        Y[mi][n] = __builtin_amdgcn_mfma_f32_16x16x32_bf16(pf, qf, Y[mi][n], 0, 0, 0);
      }
    }
  }

  // output: g = (Y + Dskip*x) * silu(z)   [z-gate fused]
  float dsk = Dskip[h];
  #pragma unroll
  for (int mi = 0; mi < 2; ++mi){
    int mt = mi ? mtB : w;
    #pragma unroll
    for (int r = 0; r < 4; ++r){
      int t = mt*16 + ((l>>4)<<2) + r;
      size_t orow = (size_t)(row0 + t)*D_INNER + h*64;
      size_t zrow = (size_t)(row0 + t)*NPAD + h*64;
      #pragma unroll
      for (int n = 0; n < 4; ++n){
        int p = n*16 + fr;
        float xv = bf2f(XTl[p*136 + t]);
        float zf = bf2f(zx[zrow + p]);
        float yv = Y[mi][n][r] + dsk*xv;
        float g  = yv * (zf / (1.f + expf(-zf)));
        yb[orow + p] = f2bf(g);
      }
    }
  }
}

// ---------------- fused RMS + (norm_w*W_out@head_w) dot on gated y ----------
__global__ __launch_bounds__(256) void k_epilogue(const unsigned short* __restrict__ yg,
                                                  const float* __restrict__ nwc,
                                                  const float* __restrict__ head_b,
                                                  float* __restrict__ out){
  int r   = blockIdx.x;
  int tid = threadIdx.x;
  bf16x8 y8 = *(const bf16x8*)(yg + (size_t)r*D_INNER + tid*8);
  float4 w0 = ((const float4*)nwc)[tid*2];
  float4 w1 = ((const float4*)nwc)[tid*2 + 1];
  float wv[8] = {w0.x, w0.y, w0.z, w0.w, w1.x, w1.y, w1.z, w1.w};
  float s2 = 0.f, sd = 0.f;
  #pragma unroll
  for (int k = 0; k < 8; ++k){
    float g = bf2f((unsigned short)y8[k]);
    s2 += g*g; sd += g*wv[k];
  }
  #pragma unroll
  for (int off = 32; off; off >>= 1){
    s2 += __shfl_down(s2, off);
    sd += __shfl_down(sd, off);
  }
  __shared__ float r2[4], rd[4];
  if ((tid & 63) == 0){ r2[tid >> 6] = s2; rd[tid >> 6] = sd; }
  __syncthreads();
  if (tid == 0){
    float t2 = r2[0] + r2[1] + r2[2] + r2[3];
    float td = rd[0] + rd[1] + rd[2] + rd[3];
    out[r] = rsqrtf(t2 * (1.f/2048.f) + 1e-5f) * td + head_b[0];
  }
}

extern "C" void kernel_launch(void* const* d_in, const int* in_sizes, int n_in,
                              void* d_out, int out_size, void* d_ws, size_t ws_size,
                              hipStream_t stream){
  const float* x       = (const float*)d_in[0];
  const float* W_in    = (const float*)d_in[1];
  const float* conv_w  = (const float*)d_in[2];
  const float* conv_b  = (const float*)d_in[3];
  const float* dt_bias = (const float*)d_in[4];
  const float* A_log   = (const float*)d_in[5];
  const float* Dskip   = (const float*)d_in[6];
  const float* norm_w  = (const float*)d_in[7];
  const float* W_out   = (const float*)d_in[8];
  const float* head_w  = (const float*)d_in[9];
  const float* head_b  = (const float*)d_in[10];
  float* out = (float*)d_out;

  char* ws = (char*)d_ws;
  unsigned short* xb   = (unsigned short*)(ws + 0);            // 16,777,216 (reused: hbuf)
  unsigned short* wt   = (unsigned short*)(ws + 16777216);     //  8,912,896 W_in^T (reused: bc16|csb|cumA)
  unsigned short* zx16 = (unsigned short*)(ws + 25690112);     // 71,303,168
  unsigned short* xbc  = (unsigned short*)(ws + 96993280);     // 33,554,432 ([r][2048] x only)
  float*          dtb  = (float*)         (ws + 132644864);    //  1,048,576
  float*          nwc  = (float*)         (ws + 134742016);    //      8,192
  unsigned short* yb   = (unsigned short*)(ws + 134750208);    // 33,554,432

  unsigned short* hbuf = xb;                                   // 2048*4096*2B
  unsigned short* bc16 = wt;                                   // 8192*128*2B = 2,097,152
  float*          csb  = (float*)(ws + 16777216 + 2097152);    // 2048*128*4B
  float*          cumA = (float*)(ws + 16777216 + 3145728);    // 8,192

  k_prep<<<13056, 256, 0, stream>>>(x, W_in, W_out, head_w, norm_w, xb, wt, nwc);
  k_gemm256<<<(NROWS/256)*(NPAD/256), 512, 0, stream>>>(xb, wt, zx16);
  k_dtcs<<<2048, 64, 0, stream>>>(zx16, dt_bias, A_log, dtb, csb, cumA);
  k_conv<<<NROWS, 256, 0, stream>>>(zx16, conv_w, conv_b, xbc, bc16);
  k_ssd1<<<2048, 256, 0, stream>>>(xbc, bc16, dtb, csb, A_log, hbuf);
  k_comb<<<256, 256, 0, stream>>>(hbuf, cumA);
  k_ssd2<<<2048, 256, 0, stream>>>(xbc, bc16, zx16, dtb, csb, A_log, Dskip, hbuf, yb);
  k_epilogue<<<NROWS, 256, 0, stream>>>(yb, nwc, head_b, out);
}